// Round 9
// baseline (381.718 us; speedup 1.0000x reference)
//
#include <hip/hip_runtime.h>

// NavierStokesLoss: fused jet-propagation (8 channels/point) through
// 4->256->256->5 tanh MLP. R9: fp8(e4m3) MFMA for GEMM2/GEMM3 (same lane
// mapping as bf16 16x16x32, half the bytes) on the proven spill-free R3
// structure. Jet tile 32 KiB -> 3 blocks/CU; W2^T 64 KB -> half the B VMEM.
// All scalar math (tanh, recombine, residual, reductions) stays f32.

#define NPTS 65536
#define BP   16
#define NBLK (NPTS / BP)      // 4096
#define KPADB 264             // byte stride of one W2^T row (256 fp8 + 8 pad)
#define W3T_OFF 135168
#define PART_OFF 143360

typedef float f32x4 __attribute__((ext_vector_type(4)));

static __device__ __forceinline__ unsigned cvtpk_fp8(float lo, float hi){
  unsigned r = 0;
  asm("v_cvt_pk_fp8_f32 %0, %1, %2" : "+v"(r) : "v"(lo), "v"(hi));
  return r;   // bytes [0]=fp8(lo), [1]=fp8(hi), high half 0
}
static __device__ __forceinline__ float fast_tanh(float x){
  float e = __builtin_amdgcn_exp2f(x * 2.8853900817779268f);   // exp(2x)
  return 1.f - 2.f * __builtin_amdgcn_rcpf(e + 1.f);
}

// W2 (256x256 f32, [k][j]) -> w2t fp8 [j][KPADB] (transposed, padded rows)
__global__ void prep_w2t(const float* __restrict__ W2, unsigned char* __restrict__ w2t){
  int kp = blockIdx.x, j = threadIdx.x;          // 128 k-pairs
  float lo = W2[(2*kp    )*256 + j];
  float hi = W2[(2*kp + 1)*256 + j];
  *(unsigned short*)(w2t + j*KPADB + 2*kp) = (unsigned short)cvtpk_fp8(lo, hi);
}
// W3 (256x5 f32, [k][n]) -> w3t fp8 [16][256] (transposed, rows 5..15 zero)
__global__ void prep_w3t(const float* __restrict__ W3, unsigned char* __restrict__ w3t){
  int n = blockIdx.x, k2 = threadIdx.x * 2;      // 16 x 128
  float lo = (n < 5) ? W3[k2*5 + n]       : 0.f;
  float hi = (n < 5) ? W3[(k2+1)*5 + n]   : 0.f;
  *(unsigned short*)(w3t + n*256 + k2) = (unsigned short)cvtpk_fp8(lo, hi);
}

// Jet-tile row layout (128 rows x 256 fp8, 256B rows, byte-XOR swizzle <<3):
//   row(p,c) = (p&8)*8 + (c&4)*8 + (p&7)*4 + (c&3)
__launch_bounds__(512, 6)
__global__ void ns_main(const float* __restrict__ pts, const float* __restrict__ times,
                        const float* __restrict__ visc,
                        const float* __restrict__ W1, const float* __restrict__ b1,
                        const float* __restrict__ b2, const float* __restrict__ b3,
                        const unsigned char* __restrict__ w2t,
                        const unsigned char* __restrict__ w3t,
                        float* __restrict__ parts){
  __shared__ __align__(16) unsigned char sA[128 * 256];   // 32 KiB

  const int t   = threadIdx.x;
  const int blk = blockIdx.x;

  // ---------------- layer 1: seed the jet, write fp8 A-tile ----------------
  {
    int p  = t >> 5;            // 16 points, 32 threads each
    int jo = (t & 31) << 3;     // 8 consecutive j per thread
    int n  = blk * BP + p;
    float z0 = pts[n*3+0], z1 = pts[n*3+1], z2 = pts[n*3+2], z3 = times[n];
    float w0v[8], w1v[8], w2v[8], w3v[8], bv[8];
    *(float4*)(w0v)   = *(const float4*)(W1 + jo);
    *(float4*)(w0v+4) = *(const float4*)(W1 + jo + 4);
    *(float4*)(w1v)   = *(const float4*)(W1 + 256 + jo);
    *(float4*)(w1v+4) = *(const float4*)(W1 + 256 + jo + 4);
    *(float4*)(w2v)   = *(const float4*)(W1 + 512 + jo);
    *(float4*)(w2v+4) = *(const float4*)(W1 + 512 + jo + 4);
    *(float4*)(w3v)   = *(const float4*)(W1 + 768 + jo);
    *(float4*)(w3v+4) = *(const float4*)(W1 + 768 + jo + 4);
    *(float4*)(bv)    = *(const float4*)(b1 + jo);
    *(float4*)(bv+4)  = *(const float4*)(b1 + jo + 4);
    float cv[8][8];
    #pragma unroll
    for (int jj = 0; jj < 8; ++jj){
      float w0 = w0v[jj], w1 = w1v[jj], w2 = w2v[jj], w3 = w3v[jj];
      float a  = bv[jj] + z0*w0 + z1*w1 + z2*w2 + z3*w3;
      float th = fast_tanh(a);
      float s  = 1.f - th*th;
      float m2 = -2.f * th * s;
      cv[0][jj] = th;
      cv[1][jj] = s*w0; cv[2][jj] = s*w1; cv[3][jj] = s*w2; cv[4][jj] = s*w3;
      cv[5][jj] = m2*w0*w0; cv[6][jj] = m2*w1*w1; cv[7][jj] = m2*w2*w2;
    }
    #pragma unroll
    for (int c = 0; c < 8; ++c){
      int row = ((p & 8) << 3) + ((c & 4) << 3) + ((p & 7) << 2) + (c & 3);
      int off = row*256 + (jo ^ ((row & 7) << 3));
      unsigned u01 = cvtpk_fp8(cv[c][0], cv[c][1]);
      unsigned u23 = cvtpk_fp8(cv[c][2], cv[c][3]);
      unsigned u45 = cvtpk_fp8(cv[c][4], cv[c][5]);
      unsigned u67 = cvtpk_fp8(cv[c][6], cv[c][7]);
      uint2 v;
      v.x = u01 | (u23 << 16);
      v.y = u45 | (u67 << 16);
      *(uint2*)(sA + off) = v;
    }
  }
  __syncthreads();

  const int wid = t >> 6, lane = t & 63;
  const int g = lane >> 4, r16 = lane & 15;
  const int wr = wid >> 2, wc = wid & 3;       // 2x4 wave grid over 128x256 C
  const int xorv = (r16 & 7) << 3;

  // ---------------- GEMM2: A(128x256) @ W2(256x256), fp8 MFMA ----------------
  f32x4 acc[4][4];
  #pragma unroll
  for (int a = 0; a < 4; ++a)
    #pragma unroll
    for (int b = 0; b < 4; ++b)
      acc[a][b] = (f32x4){0.f, 0.f, 0.f, 0.f};

  {
    int abase0 = (wr*64 + r16)*256;
    const unsigned char* bptr[4];
    #pragma unroll
    for (int nt = 0; nt < 4; ++nt)
      bptr[nt] = w2t + (wc*64 + nt*16 + r16)*KPADB + g*8;
    #pragma unroll
    for (int ks = 0; ks < 8; ++ks){
      int k0 = ks * 32;
      int X  = (k0 + (g << 3)) ^ xorv;
      long af[4], bfr[4];
      #pragma unroll
      for (int mt = 0; mt < 4; ++mt)
        af[mt] = *(const long*)(sA + abase0 + mt*4096 + X);
      #pragma unroll
      for (int nt = 0; nt < 4; ++nt)
        bfr[nt] = *(const long*)(bptr[nt] + k0);
      #pragma unroll
      for (int mt = 0; mt < 4; ++mt)
        #pragma unroll
        for (int nt = 0; nt < 4; ++nt)
          acc[mt][nt] = __builtin_amdgcn_mfma_f32_16x16x32_fp8_fp8(af[mt], bfr[nt], acc[mt][nt], 0, 0, 0);
    }
  }
  __syncthreads();   // all A-tile reads complete before overwrite

  // ------- recombine (tanh jet through layer-2), register-local, fp8 writes -------
  {
    float b2c[4];
    #pragma unroll
    for (int nt = 0; nt < 4; ++nt) b2c[nt] = b2[wc*64 + nt*16 + r16];
    // write row for channel c3 (<4): wr*64 + mt*16 + g*4 + c3 ; +32 rows (+8192B) for c3+4
    // row&7 = 4*(g&1) + c3
    int wadr[4][4];   // [nt][c3] for mt=0; +4096*mt; +8192 for c+4
    #pragma unroll
    for (int nt = 0; nt < 4; ++nt){
      int colb = wc*64 + nt*16 + r16;
      #pragma unroll
      for (int c3 = 0; c3 < 4; ++c3)
        wadr[nt][c3] = (wr*64 + g*4 + c3)*256 + (colb ^ ((((g & 1) << 2) + c3) << 3));
    }
    #pragma unroll
    for (int mt = 0; mt < 2; ++mt){
      #pragma unroll
      for (int nt = 0; nt < 4; ++nt){
        f32x4 v = acc[mt][nt];       // channels 0..3: value, dx, dy, dz
        f32x4 w = acc[mt+2][nt];     // channels 4..7: dt, dxx, dyy, dzz
        float gv = fast_tanh(v[0] + b2c[nt]);
        float s2 = 1.f - gv*gv;
        float t2 = -2.f * gv * s2;
        float r0 = gv,      r1 = s2*v[1], r2 = s2*v[2], r3 = s2*v[3];
        float r4 = s2*w[0];
        float r5 = fmaf(t2*v[1], v[1], s2*w[1]);
        float r6 = fmaf(t2*v[2], v[2], s2*w[2]);
        float r7 = fmaf(t2*v[3], v[3], s2*w[3]);
        unsigned u;
        u = cvtpk_fp8(r0, r4);
        *(unsigned char*)(sA + wadr[nt][0] + mt*4096)        = (unsigned char)u;
        *(unsigned char*)(sA + wadr[nt][0] + mt*4096 + 8192) = (unsigned char)(u >> 8);
        u = cvtpk_fp8(r1, r5);
        *(unsigned char*)(sA + wadr[nt][1] + mt*4096)        = (unsigned char)u;
        *(unsigned char*)(sA + wadr[nt][1] + mt*4096 + 8192) = (unsigned char)(u >> 8);
        u = cvtpk_fp8(r2, r6);
        *(unsigned char*)(sA + wadr[nt][2] + mt*4096)        = (unsigned char)u;
        *(unsigned char*)(sA + wadr[nt][2] + mt*4096 + 8192) = (unsigned char)(u >> 8);
        u = cvtpk_fp8(r3, r7);
        *(unsigned char*)(sA + wadr[nt][3] + mt*4096)        = (unsigned char)u;
        *(unsigned char*)(sA + wadr[nt][3] + mt*4096 + 8192) = (unsigned char)(u >> 8);
      }
    }
  }
  __syncthreads();

  // ---------------- GEMM3: B(128x256) @ W3pad(256x16), all 8 waves ----------------
  {
    f32x4 acc3 = (f32x4){0.f, 0.f, 0.f, 0.f};
    int rbase = (wid*16 + r16)*256;
    const unsigned char* w3p = w3t + r16*256 + g*8;
    #pragma unroll
    for (int ks = 0; ks < 8; ++ks){
      int k0 = ks * 32;
      int X  = (k0 + (g << 3)) ^ xorv;
      long a3  = *(const long*)(sA + rbase + X);
      long b3f = *(const long*)(w3p + k0);
      acc3 = __builtin_amdgcn_mfma_f32_16x16x32_fp8_fp8(a3, b3f, acc3, 0, 0, 0);
    }
    // write the 5 useful outputs (f32) into the first bytes of own rows
    if (r16 < 5){
      #pragma unroll
      for (int q = 0; q < 4; ++q){
        int row = wid*16 + g*4 + q;
        *(float*)(sA + row*256 + ((r16 << 2) ^ ((row & 7) << 3))) = acc3[q];
      }
    }
  }
  __syncthreads();

  // ---------------- per-point residual assembly (wave 0) ----------------
  float m_part = 0.f, c_part = 0.f;
  if (t < 16){
    int p = t, n = blk*BP + p;
    float o[8][5];
    #pragma unroll
    for (int c = 0; c < 8; ++c){
      int row = ((p & 8) << 3) + ((c & 4) << 3) + ((p & 7) << 2) + (c & 3);
      int swz = (row & 7) << 3;
      #pragma unroll
      for (int m = 0; m < 5; ++m)
        o[c][m] = *(const float*)(sA + row*256 + ((m << 2) ^ swz));
    }
    #pragma unroll
    for (int m = 0; m < 5; ++m) o[0][m] += b3[m];  // bias only on value channel

    float u0 = o[0][0], u1 = o[0][1], u2 = o[0][2];
    float rho = 1000.f * (1.f + 0.1f * fast_tanh(o[0][4]));
    float rr  = __builtin_amdgcn_rcpf(rho);
    float vis = visc[n];

    float conv0 = u0*o[1][0] + u1*o[2][0] + u2*o[3][0];
    float conv1 = u0*o[1][1] + u1*o[2][1] + u2*o[3][1];
    float conv2 = u0*o[1][2] + u1*o[2][2] + u2*o[3][2];
    float lap0 = o[5][0] + o[6][0] + o[7][0];
    float lap1 = o[5][1] + o[6][1] + o[7][1];
    float lap2 = o[5][2] + o[6][2] + o[7][2];
    float R0 = o[4][0] + conv0 + o[1][3]*rr - vis*lap0;
    float R1 = o[4][1] + conv1 + o[2][3]*rr - vis*lap1 + 9.81f;
    float R2 = o[4][2] + conv2 + o[3][3]*rr - vis*lap2;
    float Rc = o[1][0] + o[2][1] + o[3][2];

    m_part = R0*R0 + R1*R1 + R2*R2;
    c_part = Rc*Rc;
  }
  if (t < 64){
    #pragma unroll
    for (int off = 1; off < 16; off <<= 1){
      m_part += __shfl_xor(m_part, off, 64);
      c_part += __shfl_xor(c_part, off, 64);
    }
    if (t == 0){
      float2 pr; pr.x = m_part; pr.y = c_part;
      *(float2*)(parts + blk*2) = pr;
    }
  }
}

__global__ void ns_reduce(const float* __restrict__ parts, float* __restrict__ out){
  int t = threadIdx.x;
  float a = 0.f, b = 0.f;
  for (int i = t; i < NBLK; i += 256){ a += parts[2*i]; b += parts[2*i + 1]; }
  #pragma unroll
  for (int off = 32; off; off >>= 1){
    a += __shfl_down(a, off, 64);
    b += __shfl_down(b, off, 64);
  }
  __shared__ float sa[4], sb[4];
  int wid = t >> 6, lane = t & 63;
  if (lane == 0){ sa[wid] = a; sb[wid] = b; }
  __syncthreads();
  if (t == 0){
    float A = sa[0] + sa[1] + sa[2] + sa[3];
    float B = sb[0] + sb[1] + sb[2] + sb[3];
    float mom  = A / (float)NPTS;
    float cont = B / (float)NPTS;
    out[0] = mom + 10.f * cont;
    out[1] = mom;
    out[2] = cont;
  }
}

extern "C" void kernel_launch(void* const* d_in, const int* in_sizes, int n_in,
                              void* d_out, int out_size, void* d_ws, size_t ws_size,
                              hipStream_t stream) {
  const float* pts   = (const float*)d_in[0];
  const float* times = (const float*)d_in[1];
  const float* visc  = (const float*)d_in[2];
  const float* W1    = (const float*)d_in[3];
  const float* b1    = (const float*)d_in[4];
  const float* W2    = (const float*)d_in[5];
  const float* b2    = (const float*)d_in[6];
  const float* W3    = (const float*)d_in[7];
  const float* b3    = (const float*)d_in[8];
  float* out = (float*)d_out;

  unsigned char* w2t = (unsigned char*)d_ws;
  unsigned char* w3t = (unsigned char*)d_ws + W3T_OFF;
  float* parts       = (float*)((char*)d_ws + PART_OFF);

  prep_w2t<<<128, 256, 0, stream>>>(W2, w2t);
  prep_w3t<<<16, 128, 0, stream>>>(W3, w3t);
  ns_main<<<NBLK, 512, 0, stream>>>(pts, times, visc, W1, b1, b2, b3, w2t, w3t, parts);
  ns_reduce<<<1, 256, 0, stream>>>(parts, out);
}

// Round 10
// 137.949 us; speedup vs baseline: 2.7671x; 2.7671x over previous
//
#include <hip/hip_runtime.h>

// NavierStokesLoss: fused jet-propagation (8 channels/point) through
// 4->256->256->5 tanh MLP. R10 = R9 (fp8 e4m3 MFMA, 32 KiB jet tile, 64 KB
// W2^T) with the launch-bounds spill bug fixed: __launch_bounds__(512,4)
// gives a 128-reg cap (acc[4][4]=64 + fragments fit; R9's (512,6) forced an
// ~85-reg cap and spilled the accumulators -> 1 GB scratch traffic).

#define NPTS 65536
#define BP   16
#define NBLK (NPTS / BP)      // 4096
#define KPADB 264             // byte stride of one W2^T row (256 fp8 + 8 pad)
#define W3T_OFF 135168
#define PART_OFF 143360

typedef float f32x4 __attribute__((ext_vector_type(4)));

static __device__ __forceinline__ unsigned cvtpk_fp8(float lo, float hi){
  unsigned r = 0;
  asm("v_cvt_pk_fp8_f32 %0, %1, %2" : "+v"(r) : "v"(lo), "v"(hi));
  return r;   // bytes [0]=fp8(lo), [1]=fp8(hi)
}
static __device__ __forceinline__ float fast_tanh(float x){
  float e = __builtin_amdgcn_exp2f(x * 2.8853900817779268f);   // exp(2x)
  return 1.f - 2.f * __builtin_amdgcn_rcpf(e + 1.f);
}

// W2 (256x256 f32, [k][j]) -> w2t fp8 [j][KPADB] (transposed, padded rows)
__global__ void prep_w2t(const float* __restrict__ W2, unsigned char* __restrict__ w2t){
  int kp = blockIdx.x, j = threadIdx.x;          // 128 k-pairs
  float lo = W2[(2*kp    )*256 + j];
  float hi = W2[(2*kp + 1)*256 + j];
  *(unsigned short*)(w2t + j*KPADB + 2*kp) = (unsigned short)cvtpk_fp8(lo, hi);
}
// W3 (256x5 f32, [k][n]) -> w3t fp8 [16][256] (transposed, rows 5..15 zero)
__global__ void prep_w3t(const float* __restrict__ W3, unsigned char* __restrict__ w3t){
  int n = blockIdx.x, k2 = threadIdx.x * 2;      // 16 x 128
  float lo = (n < 5) ? W3[k2*5 + n]       : 0.f;
  float hi = (n < 5) ? W3[(k2+1)*5 + n]   : 0.f;
  *(unsigned short*)(w3t + n*256 + k2) = (unsigned short)cvtpk_fp8(lo, hi);
}

// Jet-tile row layout (128 rows x 256 fp8, 256B rows, byte-XOR swizzle <<3):
//   row(p,c) = (p&8)*8 + (c&4)*8 + (p&7)*4 + (c&3)
__launch_bounds__(512, 4)
__global__ void ns_main(const float* __restrict__ pts, const float* __restrict__ times,
                        const float* __restrict__ visc,
                        const float* __restrict__ W1, const float* __restrict__ b1,
                        const float* __restrict__ b2, const float* __restrict__ b3,
                        const unsigned char* __restrict__ w2t,
                        const unsigned char* __restrict__ w3t,
                        float* __restrict__ parts){
  __shared__ __align__(16) unsigned char sA[128 * 256];   // 32 KiB

  const int t   = threadIdx.x;
  const int blk = blockIdx.x;

  // ---------------- layer 1: seed the jet, write fp8 A-tile ----------------
  {
    int p  = t >> 5;            // 16 points, 32 threads each
    int jo = (t & 31) << 3;     // 8 consecutive j per thread
    int n  = blk * BP + p;
    float z0 = pts[n*3+0], z1 = pts[n*3+1], z2 = pts[n*3+2], z3 = times[n];
    float w0v[8], w1v[8], w2v[8], w3v[8], bv[8];
    *(float4*)(w0v)   = *(const float4*)(W1 + jo);
    *(float4*)(w0v+4) = *(const float4*)(W1 + jo + 4);
    *(float4*)(w1v)   = *(const float4*)(W1 + 256 + jo);
    *(float4*)(w1v+4) = *(const float4*)(W1 + 256 + jo + 4);
    *(float4*)(w2v)   = *(const float4*)(W1 + 512 + jo);
    *(float4*)(w2v+4) = *(const float4*)(W1 + 512 + jo + 4);
    *(float4*)(w3v)   = *(const float4*)(W1 + 768 + jo);
    *(float4*)(w3v+4) = *(const float4*)(W1 + 768 + jo + 4);
    *(float4*)(bv)    = *(const float4*)(b1 + jo);
    *(float4*)(bv+4)  = *(const float4*)(b1 + jo + 4);
    float cv[8][8];
    #pragma unroll
    for (int jj = 0; jj < 8; ++jj){
      float w0 = w0v[jj], w1 = w1v[jj], w2 = w2v[jj], w3 = w3v[jj];
      float a  = bv[jj] + z0*w0 + z1*w1 + z2*w2 + z3*w3;
      float th = fast_tanh(a);
      float s  = 1.f - th*th;
      float m2 = -2.f * th * s;
      cv[0][jj] = th;
      cv[1][jj] = s*w0; cv[2][jj] = s*w1; cv[3][jj] = s*w2; cv[4][jj] = s*w3;
      cv[5][jj] = m2*w0*w0; cv[6][jj] = m2*w1*w1; cv[7][jj] = m2*w2*w2;
    }
    #pragma unroll
    for (int c = 0; c < 8; ++c){
      int row = ((p & 8) << 3) + ((c & 4) << 3) + ((p & 7) << 2) + (c & 3);
      int off = row*256 + (jo ^ ((row & 7) << 3));
      unsigned u01 = cvtpk_fp8(cv[c][0], cv[c][1]);
      unsigned u23 = cvtpk_fp8(cv[c][2], cv[c][3]);
      unsigned u45 = cvtpk_fp8(cv[c][4], cv[c][5]);
      unsigned u67 = cvtpk_fp8(cv[c][6], cv[c][7]);
      uint2 v;
      v.x = u01 | (u23 << 16);
      v.y = u45 | (u67 << 16);
      *(uint2*)(sA + off) = v;
    }
  }
  __syncthreads();

  const int wid = t >> 6, lane = t & 63;
  const int g = lane >> 4, r16 = lane & 15;
  const int wr = wid >> 2, wc = wid & 3;       // 2x4 wave grid over 128x256 C
  const int xorv = (r16 & 7) << 3;

  // ---------------- GEMM2: A(128x256) @ W2(256x256), fp8 MFMA ----------------
  f32x4 acc[4][4];
  #pragma unroll
  for (int a = 0; a < 4; ++a)
    #pragma unroll
    for (int b = 0; b < 4; ++b)
      acc[a][b] = (f32x4){0.f, 0.f, 0.f, 0.f};

  {
    int abase0 = (wr*64 + r16)*256;
    const unsigned char* bptr[4];
    #pragma unroll
    for (int nt = 0; nt < 4; ++nt)
      bptr[nt] = w2t + (wc*64 + nt*16 + r16)*KPADB + g*8;
    #pragma unroll
    for (int ks = 0; ks < 8; ++ks){
      int k0 = ks * 32;
      int X  = (k0 + (g << 3)) ^ xorv;
      long af[4], bfr[4];
      #pragma unroll
      for (int mt = 0; mt < 4; ++mt)
        af[mt] = *(const long*)(sA + abase0 + mt*4096 + X);
      #pragma unroll
      for (int nt = 0; nt < 4; ++nt)
        bfr[nt] = *(const long*)(bptr[nt] + k0);
      #pragma unroll
      for (int mt = 0; mt < 4; ++mt)
        #pragma unroll
        for (int nt = 0; nt < 4; ++nt)
          acc[mt][nt] = __builtin_amdgcn_mfma_f32_16x16x32_fp8_fp8(af[mt], bfr[nt], acc[mt][nt], 0, 0, 0);
    }
  }
  __syncthreads();   // all A-tile reads complete before overwrite

  // ------- recombine (tanh jet through layer-2), register-local, fp8 writes -------
  {
    float b2c[4];
    #pragma unroll
    for (int nt = 0; nt < 4; ++nt) b2c[nt] = b2[wc*64 + nt*16 + r16];
    // write row for channel c3 (<4): wr*64 + mt*16 + g*4 + c3 ; +32 rows (+8192B) for c3+4
    // row&7 = 4*(g&1) + c3
    int wadr[4][4];   // [nt][c3] for mt=0; +4096*mt; +8192 for c+4
    #pragma unroll
    for (int nt = 0; nt < 4; ++nt){
      int colb = wc*64 + nt*16 + r16;
      #pragma unroll
      for (int c3 = 0; c3 < 4; ++c3)
        wadr[nt][c3] = (wr*64 + g*4 + c3)*256 + (colb ^ ((((g & 1) << 2) + c3) << 3));
    }
    #pragma unroll
    for (int mt = 0; mt < 2; ++mt){
      #pragma unroll
      for (int nt = 0; nt < 4; ++nt){
        f32x4 v = acc[mt][nt];       // channels 0..3: value, dx, dy, dz
        f32x4 w = acc[mt+2][nt];     // channels 4..7: dt, dxx, dyy, dzz
        float gv = fast_tanh(v[0] + b2c[nt]);
        float s2 = 1.f - gv*gv;
        float t2 = -2.f * gv * s2;
        float r0 = gv,      r1 = s2*v[1], r2 = s2*v[2], r3 = s2*v[3];
        float r4 = s2*w[0];
        float r5 = fmaf(t2*v[1], v[1], s2*w[1]);
        float r6 = fmaf(t2*v[2], v[2], s2*w[2]);
        float r7 = fmaf(t2*v[3], v[3], s2*w[3]);
        unsigned u;
        u = cvtpk_fp8(r0, r4);
        *(unsigned char*)(sA + wadr[nt][0] + mt*4096)        = (unsigned char)u;
        *(unsigned char*)(sA + wadr[nt][0] + mt*4096 + 8192) = (unsigned char)(u >> 8);
        u = cvtpk_fp8(r1, r5);
        *(unsigned char*)(sA + wadr[nt][1] + mt*4096)        = (unsigned char)u;
        *(unsigned char*)(sA + wadr[nt][1] + mt*4096 + 8192) = (unsigned char)(u >> 8);
        u = cvtpk_fp8(r2, r6);
        *(unsigned char*)(sA + wadr[nt][2] + mt*4096)        = (unsigned char)u;
        *(unsigned char*)(sA + wadr[nt][2] + mt*4096 + 8192) = (unsigned char)(u >> 8);
        u = cvtpk_fp8(r3, r7);
        *(unsigned char*)(sA + wadr[nt][3] + mt*4096)        = (unsigned char)u;
        *(unsigned char*)(sA + wadr[nt][3] + mt*4096 + 8192) = (unsigned char)(u >> 8);
      }
    }
  }
  __syncthreads();

  // ---------------- GEMM3: B(128x256) @ W3pad(256x16), all 8 waves ----------------
  {
    f32x4 acc3 = (f32x4){0.f, 0.f, 0.f, 0.f};
    int rbase = (wid*16 + r16)*256;
    const unsigned char* w3p = w3t + r16*256 + g*8;
    #pragma unroll
    for (int ks = 0; ks < 8; ++ks){
      int k0 = ks * 32;
      int X  = (k0 + (g << 3)) ^ xorv;
      long a3  = *(const long*)(sA + rbase + X);
      long b3f = *(const long*)(w3p + k0);
      acc3 = __builtin_amdgcn_mfma_f32_16x16x32_fp8_fp8(a3, b3f, acc3, 0, 0, 0);
    }
    // write the 5 useful outputs (f32) into the first bytes of own rows
    if (r16 < 5){
      #pragma unroll
      for (int q = 0; q < 4; ++q){
        int row = wid*16 + g*4 + q;
        *(float*)(sA + row*256 + ((r16 << 2) ^ ((row & 7) << 3))) = acc3[q];
      }
    }
  }
  __syncthreads();

  // ---------------- per-point residual assembly (wave 0) ----------------
  float m_part = 0.f, c_part = 0.f;
  if (t < 16){
    int p = t, n = blk*BP + p;
    float o[8][5];
    #pragma unroll
    for (int c = 0; c < 8; ++c){
      int row = ((p & 8) << 3) + ((c & 4) << 3) + ((p & 7) << 2) + (c & 3);
      int swz = (row & 7) << 3;
      #pragma unroll
      for (int m = 0; m < 5; ++m)
        o[c][m] = *(const float*)(sA + row*256 + ((m << 2) ^ swz));
    }
    #pragma unroll
    for (int m = 0; m < 5; ++m) o[0][m] += b3[m];  // bias only on value channel

    float u0 = o[0][0], u1 = o[0][1], u2 = o[0][2];
    float rho = 1000.f * (1.f + 0.1f * fast_tanh(o[0][4]));
    float rr  = __builtin_amdgcn_rcpf(rho);
    float vis = visc[n];

    float conv0 = u0*o[1][0] + u1*o[2][0] + u2*o[3][0];
    float conv1 = u0*o[1][1] + u1*o[2][1] + u2*o[3][1];
    float conv2 = u0*o[1][2] + u1*o[2][2] + u2*o[3][2];
    float lap0 = o[5][0] + o[6][0] + o[7][0];
    float lap1 = o[5][1] + o[6][1] + o[7][1];
    float lap2 = o[5][2] + o[6][2] + o[7][2];
    float R0 = o[4][0] + conv0 + o[1][3]*rr - vis*lap0;
    float R1 = o[4][1] + conv1 + o[2][3]*rr - vis*lap1 + 9.81f;
    float R2 = o[4][2] + conv2 + o[3][3]*rr - vis*lap2;
    float Rc = o[1][0] + o[2][1] + o[3][2];

    m_part = R0*R0 + R1*R1 + R2*R2;
    c_part = Rc*Rc;
  }
  if (t < 64){
    #pragma unroll
    for (int off = 1; off < 16; off <<= 1){
      m_part += __shfl_xor(m_part, off, 64);
      c_part += __shfl_xor(c_part, off, 64);
    }
    if (t == 0){
      float2 pr; pr.x = m_part; pr.y = c_part;
      *(float2*)(parts + blk*2) = pr;
    }
  }
}

__global__ void ns_reduce(const float* __restrict__ parts, float* __restrict__ out){
  int t = threadIdx.x;
  float a = 0.f, b = 0.f;
  for (int i = t; i < NBLK; i += 256){ a += parts[2*i]; b += parts[2*i + 1]; }
  #pragma unroll
  for (int off = 32; off; off >>= 1){
    a += __shfl_down(a, off, 64);
    b += __shfl_down(b, off, 64);
  }
  __shared__ float sa[4], sb[4];
  int wid = t >> 6, lane = t & 63;
  if (lane == 0){ sa[wid] = a; sb[wid] = b; }
  __syncthreads();
  if (t == 0){
    float A = sa[0] + sa[1] + sa[2] + sa[3];
    float B = sb[0] + sb[1] + sb[2] + sb[3];
    float mom  = A / (float)NPTS;
    float cont = B / (float)NPTS;
    out[0] = mom + 10.f * cont;
    out[1] = mom;
    out[2] = cont;
  }
}

extern "C" void kernel_launch(void* const* d_in, const int* in_sizes, int n_in,
                              void* d_out, int out_size, void* d_ws, size_t ws_size,
                              hipStream_t stream) {
  const float* pts   = (const float*)d_in[0];
  const float* times = (const float*)d_in[1];
  const float* visc  = (const float*)d_in[2];
  const float* W1    = (const float*)d_in[3];
  const float* b1    = (const float*)d_in[4];
  const float* W2    = (const float*)d_in[5];
  const float* b2    = (const float*)d_in[6];
  const float* W3    = (const float*)d_in[7];
  const float* b3    = (const float*)d_in[8];
  float* out = (float*)d_out;

  unsigned char* w2t = (unsigned char*)d_ws;
  unsigned char* w3t = (unsigned char*)d_ws + W3T_OFF;
  float* parts       = (float*)((char*)d_ws + PART_OFF);

  prep_w2t<<<128, 256, 0, stream>>>(W2, w2t);
  prep_w3t<<<16, 128, 0, stream>>>(W3, w3t);
  ns_main<<<NBLK, 512, 0, stream>>>(pts, times, visc, W1, b1, b2, b3, w2t, w3t, parts);
  ns_reduce<<<1, 256, 0, stream>>>(parts, out);
}

// Round 11
// 120.183 us; speedup vs baseline: 3.1761x; 1.1478x over previous
//
#include <hip/hip_runtime.h>

// NavierStokesLoss: fused jet-propagation (8 channels/point) through
// 4->256->256->5 tanh MLP. R11: fp8 MFMA (validated R9/R10, absmax 0.002),
// half-size blocks: 256 threads / 4 waves / 8 points / 16 KiB LDS.
//  - wave grid 1x4 (wave wid owns cols wid*64): W2 read once per 8 pts
//    (same B-traffic/point as R10), acc[4][4].
//  - GEMM3 + residual tail fused per-wave in registers (R6's validated
//    shfl assembly, fp8 reads): no G3 writeback, no serial tail phase.
//  - 4 barriers/block, 4 blocks/CU co-resident -> natural phase mixing.

#define NPTS 65536
#define BP   8
#define NBLK (NPTS / BP)      // 8192
#define KPADB 264             // byte stride of one W2^T row (256 fp8 + 8 pad)
#define W3T_OFF 135168
#define PART_OFF 143360

typedef float f32x4 __attribute__((ext_vector_type(4)));

static __device__ __forceinline__ unsigned cvtpk_fp8(float lo, float hi){
  unsigned r = 0;
  asm("v_cvt_pk_fp8_f32 %0, %1, %2" : "+v"(r) : "v"(lo), "v"(hi));
  return r;   // bytes [0]=fp8(lo), [1]=fp8(hi)
}
static __device__ __forceinline__ float fast_tanh(float x){
  float e = __builtin_amdgcn_exp2f(x * 2.8853900817779268f);   // exp(2x)
  return 1.f - 2.f * __builtin_amdgcn_rcpf(e + 1.f);
}

// W2 (256x256 f32, [k][j]) -> w2t fp8 [j][KPADB] (transposed, padded rows)
__global__ void prep_w2t(const float* __restrict__ W2, unsigned char* __restrict__ w2t){
  int kp = blockIdx.x, j = threadIdx.x;          // 128 k-pairs
  float lo = W2[(2*kp    )*256 + j];
  float hi = W2[(2*kp + 1)*256 + j];
  *(unsigned short*)(w2t + j*KPADB + 2*kp) = (unsigned short)cvtpk_fp8(lo, hi);
}
// W3 (256x5 f32, [k][n]) -> w3t fp8 [16][256] (transposed, rows 5..15 zero)
__global__ void prep_w3t(const float* __restrict__ W3, unsigned char* __restrict__ w3t){
  int n = blockIdx.x, k2 = threadIdx.x * 2;      // 16 x 128
  float lo = (n < 5) ? W3[k2*5 + n]       : 0.f;
  float hi = (n < 5) ? W3[(k2+1)*5 + n]   : 0.f;
  *(unsigned short*)(w3t + n*256 + k2) = (unsigned short)cvtpk_fp8(lo, hi);
}

// Jet-tile row layout (64 rows x 256 fp8, 256B rows, byte-XOR swizzle <<3):
//   row(p,c) = (p&4)*8 + (c&4)*4 + (p&3)*4 + (c&3)
__launch_bounds__(256, 4)
__global__ void ns_main(const float* __restrict__ pts, const float* __restrict__ times,
                        const float* __restrict__ visc,
                        const float* __restrict__ W1, const float* __restrict__ b1,
                        const float* __restrict__ b2, const float* __restrict__ b3,
                        const unsigned char* __restrict__ w2t,
                        const unsigned char* __restrict__ w3t,
                        float* __restrict__ parts){
  __shared__ __align__(16) unsigned char sA[64 * 256];   // 16 KiB
  __shared__ float red[8];

  const int t   = threadIdx.x;
  const int blk = blockIdx.x;

  // ---------------- layer 1: seed the jet, write fp8 A-tile ----------------
  {
    int p  = t >> 5;            // 8 points, 32 threads each
    int jo = (t & 31) << 3;     // 8 consecutive j per thread
    int n  = blk * BP + p;
    float z0 = pts[n*3+0], z1 = pts[n*3+1], z2 = pts[n*3+2], z3 = times[n];
    float w0v[8], w1v[8], w2v[8], w3v[8], bv[8];
    *(float4*)(w0v)   = *(const float4*)(W1 + jo);
    *(float4*)(w0v+4) = *(const float4*)(W1 + jo + 4);
    *(float4*)(w1v)   = *(const float4*)(W1 + 256 + jo);
    *(float4*)(w1v+4) = *(const float4*)(W1 + 256 + jo + 4);
    *(float4*)(w2v)   = *(const float4*)(W1 + 512 + jo);
    *(float4*)(w2v+4) = *(const float4*)(W1 + 512 + jo + 4);
    *(float4*)(w3v)   = *(const float4*)(W1 + 768 + jo);
    *(float4*)(w3v+4) = *(const float4*)(W1 + 768 + jo + 4);
    *(float4*)(bv)    = *(const float4*)(b1 + jo);
    *(float4*)(bv+4)  = *(const float4*)(b1 + jo + 4);
    float th[8], sg[8], m2[8];
    #pragma unroll
    for (int jj = 0; jj < 8; ++jj){
      float a  = bv[jj] + z0*w0v[jj] + z1*w1v[jj] + z2*w2v[jj] + z3*w3v[jj];
      float h  = fast_tanh(a);
      th[jj] = h; sg[jj] = 1.f - h*h; m2[jj] = -2.f*h*sg[jj];
    }
    #pragma unroll
    for (int c = 0; c < 8; ++c){
      float x[8];
      #pragma unroll
      for (int jj = 0; jj < 8; ++jj){
        float v;
        if      (c == 0) v = th[jj];
        else if (c == 1) v = sg[jj]*w0v[jj];
        else if (c == 2) v = sg[jj]*w1v[jj];
        else if (c == 3) v = sg[jj]*w2v[jj];
        else if (c == 4) v = sg[jj]*w3v[jj];
        else if (c == 5) v = m2[jj]*w0v[jj]*w0v[jj];
        else if (c == 6) v = m2[jj]*w1v[jj]*w1v[jj];
        else             v = m2[jj]*w2v[jj]*w2v[jj];
        x[jj] = v;
      }
      int row = ((p & 4) << 3) + ((c & 4) << 2) + ((p & 3) << 2) + (c & 3);
      int off = row*256 + (jo ^ ((row & 7) << 3));
      uint2 v2;
      v2.x = cvtpk_fp8(x[0], x[1]) | (cvtpk_fp8(x[2], x[3]) << 16);
      v2.y = cvtpk_fp8(x[4], x[5]) | (cvtpk_fp8(x[6], x[7]) << 16);
      *(uint2*)(sA + off) = v2;
    }
  }
  __syncthreads();

  const int wid = t >> 6, lane = t & 63;
  const int g = lane >> 4, r16 = lane & 15;
  const int xorv = (r16 & 7) << 3;

  // ---------------- GEMM2: A(64x256) @ W2 cols wid*64..+63, fp8 MFMA ----------------
  f32x4 acc[4][4];
  #pragma unroll
  for (int a = 0; a < 4; ++a)
    #pragma unroll
    for (int b = 0; b < 4; ++b)
      acc[a][b] = (f32x4){0.f, 0.f, 0.f, 0.f};

  {
    int abase = r16*256;
    const unsigned char* bptr[4];
    #pragma unroll
    for (int nt = 0; nt < 4; ++nt)
      bptr[nt] = w2t + (wid*64 + nt*16 + r16)*KPADB + g*8;
    #pragma unroll
    for (int ks = 0; ks < 8; ++ks){
      int k0 = ks * 32;
      int X  = (k0 + (g << 3)) ^ xorv;
      long af[4], bfr[4];
      #pragma unroll
      for (int mt = 0; mt < 4; ++mt)
        af[mt] = *(const long*)(sA + abase + mt*4096 + X);
      #pragma unroll
      for (int nt = 0; nt < 4; ++nt)
        bfr[nt] = *(const long*)(bptr[nt] + k0);
      __builtin_amdgcn_s_setprio(1);
      #pragma unroll
      for (int mt = 0; mt < 4; ++mt)
        #pragma unroll
        for (int nt = 0; nt < 4; ++nt)
          acc[mt][nt] = __builtin_amdgcn_mfma_f32_16x16x32_fp8_fp8(af[mt], bfr[nt], acc[mt][nt], 0, 0, 0);
      __builtin_amdgcn_s_setprio(0);
    }
  }
  __syncthreads();   // all A-tile reads complete before overwrite

  // ------- recombine (tanh jet through layer-2), register-local, fp8 writes -------
  {
    float b2c[4];
    #pragma unroll
    for (int nt = 0; nt < 4; ++nt) b2c[nt] = b2[wid*64 + nt*16 + r16];
    // pr=0: pts 0-3 (acc[0]=ch0-3, acc[1]=ch4-7); pr=1: pts 4-7 (acc[2],acc[3])
    // write row (ch<4): pr*32 + g*4 + c3 ; +16 rows (+4096B) for ch+4
    int wadr[4][4];
    #pragma unroll
    for (int nt = 0; nt < 4; ++nt){
      int colb = wid*64 + nt*16 + r16;
      #pragma unroll
      for (int c3 = 0; c3 < 4; ++c3)
        wadr[nt][c3] = (g*4 + c3)*256 + (colb ^ ((((g & 1) << 2) + c3) << 3));
    }
    #pragma unroll
    for (int pr = 0; pr < 2; ++pr){
      #pragma unroll
      for (int nt = 0; nt < 4; ++nt){
        f32x4 v = acc[2*pr][nt];     // channels 0..3: value, dx, dy, dz
        f32x4 w = acc[2*pr+1][nt];   // channels 4..7: dt, dxx, dyy, dzz
        float gv = fast_tanh(v[0] + b2c[nt]);
        float s2 = 1.f - gv*gv;
        float t2 = -2.f * gv * s2;
        float r0 = gv,      r1 = s2*v[1], r2 = s2*v[2], r3 = s2*v[3];
        float r4 = s2*w[0];
        float r5 = fmaf(t2*v[1], v[1], s2*w[1]);
        float r6 = fmaf(t2*v[2], v[2], s2*w[2]);
        float r7 = fmaf(t2*v[3], v[3], s2*w[3]);
        unsigned u;
        u = cvtpk_fp8(r0, r4);
        *(unsigned char*)(sA + wadr[nt][0] + pr*8192)        = (unsigned char)u;
        *(unsigned char*)(sA + wadr[nt][0] + pr*8192 + 4096) = (unsigned char)(u >> 8);
        u = cvtpk_fp8(r1, r5);
        *(unsigned char*)(sA + wadr[nt][1] + pr*8192)        = (unsigned char)u;
        *(unsigned char*)(sA + wadr[nt][1] + pr*8192 + 4096) = (unsigned char)(u >> 8);
        u = cvtpk_fp8(r2, r6);
        *(unsigned char*)(sA + wadr[nt][2] + pr*8192)        = (unsigned char)u;
        *(unsigned char*)(sA + wadr[nt][2] + pr*8192 + 4096) = (unsigned char)(u >> 8);
        u = cvtpk_fp8(r3, r7);
        *(unsigned char*)(sA + wadr[nt][3] + pr*8192)        = (unsigned char)u;
        *(unsigned char*)(sA + wadr[nt][3] + pr*8192 + 4096) = (unsigned char)(u >> 8);
      }
    }
  }
  __syncthreads();

  // ---- GEMM3 + in-register residual tail (R6-validated shfl assembly) ----
  // wave wid owns points 2*wid, 2*wid+1. Lane r16 bits: [1:0]=c3, [2]=pt
  // parity, [3]=channel half. A-frag row r16 <-> jrow(r16).
  float accM = 0.f, accC = 0.f;
  {
    const int ptL  = 2*wid + ((r16 >> 2) & 1);
    const int jrow = ((ptL & 4) << 3) + ((ptL & 3) << 2) + (r16 & 3) + ((r16 >> 3) << 4);
    const int g3off = jrow * 256;
    const int g3sw  = (jrow & 7) << 3;
    const unsigned char* w3p = w3t + r16*256 + g*8;
    const float b3v = (r16 < 5) ? b3[r16] : 0.f;

    f32x4 a3 = (f32x4){0.f, 0.f, 0.f, 0.f};
    #pragma unroll
    for (int ks = 0; ks < 8; ++ks){
      int k0 = ks * 32;
      int X  = (k0 + (g << 3)) ^ g3sw;
      long av  = *(const long*)(sA + g3off + X);
      long bv3 = *(const long*)(w3p + k0);
      a3 = __builtin_amdgcn_mfma_f32_16x16x32_fp8_fp8(av, bv3, a3, 0, 0, 0);
    }
    float o4 = __shfl_xor(a3[0], 32, 64);
    float o5 = __shfl_xor(a3[1], 32, 64);
    float o6 = __shfl_xor(a3[2], 32, 64);
    float o7 = __shfl_xor(a3[3], 32, 64);
    float o0 = a3[0] + b3v, o1 = a3[1], o2 = a3[2], o3 = a3[3];
    int sl = lane & 16;
    float u0 = __shfl(o0, sl | 0, 64);
    float u1 = __shfl(o0, sl | 1, 64);
    float u2 = __shfl(o0, sl | 2, 64);
    float rhoA = __shfl(o0, sl | 4, 64);
    float gpx = __shfl(o1, sl | 3, 64);
    float gpy = __shfl(o2, sl | 3, 64);
    float gpz = __shfl(o3, sl | 3, 64);
    float c00 = __shfl(o1, sl | 0, 64);
    float c11 = __shfl(o2, sl | 1, 64);
    float c22 = __shfl(o3, sl | 2, 64);
    float rho = 1000.f * (1.f + 0.1f * fast_tanh(rhoA));
    float rr  = __builtin_amdgcn_rcpf(rho);
    float vis = visc[blk*BP + ptL];
    float lap = o5 + o6 + o7;
    float cv  = u0*o1 + u1*o2 + u2*o3;
    float gp  = (r16 == 0) ? gpx : ((r16 == 1) ? gpy : gpz);
    float R   = o4 + cv + gp*rr - vis*lap + ((r16 == 1) ? 9.81f : 0.f);
    if (lane < 32){
      if (r16 < 3) accM += R*R;
      else if (r16 == 3){ float Rc = c00 + c11 + c22; accC += Rc*Rc; }
    }
  }

  // ---------------- block reduction (deterministic) ----------------
  #pragma unroll
  for (int off = 1; off < 64; off <<= 1){
    accM += __shfl_xor(accM, off, 64);
    accC += __shfl_xor(accC, off, 64);
  }
  if (lane == 0){ red[wid*2] = accM; red[wid*2+1] = accC; }
  __syncthreads();
  if (t == 0){
    float m = red[0] + red[2] + red[4] + red[6];
    float c = red[1] + red[3] + red[5] + red[7];
    float2 pr; pr.x = m; pr.y = c;
    *(float2*)(parts + blk*2) = pr;
  }
}

__global__ void ns_reduce(const float* __restrict__ parts, float* __restrict__ out){
  int t = threadIdx.x;
  float a = 0.f, b = 0.f;
  for (int i = t; i < NBLK; i += 256){ a += parts[2*i]; b += parts[2*i + 1]; }
  #pragma unroll
  for (int off = 32; off; off >>= 1){
    a += __shfl_down(a, off, 64);
    b += __shfl_down(b, off, 64);
  }
  __shared__ float sa[4], sb[4];
  int wid = t >> 6, lane = t & 63;
  if (lane == 0){ sa[wid] = a; sb[wid] = b; }
  __syncthreads();
  if (t == 0){
    float A = sa[0] + sa[1] + sa[2] + sa[3];
    float B = sb[0] + sb[1] + sb[2] + sb[3];
    float mom  = A / (float)NPTS;
    float cont = B / (float)NPTS;
    out[0] = mom + 10.f * cont;
    out[1] = mom;
    out[2] = cont;
  }
}

extern "C" void kernel_launch(void* const* d_in, const int* in_sizes, int n_in,
                              void* d_out, int out_size, void* d_ws, size_t ws_size,
                              hipStream_t stream) {
  const float* pts   = (const float*)d_in[0];
  const float* times = (const float*)d_in[1];
  const float* visc  = (const float*)d_in[2];
  const float* W1    = (const float*)d_in[3];
  const float* b1    = (const float*)d_in[4];
  const float* W2    = (const float*)d_in[5];
  const float* b2    = (const float*)d_in[6];
  const float* W3    = (const float*)d_in[7];
  const float* b3    = (const float*)d_in[8];
  float* out = (float*)d_out;

  unsigned char* w2t = (unsigned char*)d_ws;
  unsigned char* w3t = (unsigned char*)d_ws + W3T_OFF;
  float* parts       = (float*)((char*)d_ws + PART_OFF);

  prep_w2t<<<128, 256, 0, stream>>>(W2, w2t);
  prep_w3t<<<16, 128, 0, stream>>>(W3, w3t);
  ns_main<<<NBLK, 256, 0, stream>>>(pts, times, visc, W1, b1, b2, b3, w2t, w3t, parts);
  ns_reduce<<<1, 256, 0, stream>>>(parts, out);
}